// Round 12
// baseline (189.693 us; speedup 1.0000x reference)
//
#include <hip/hip_runtime.h>

#define B_ROWS 262144
#define TPB 1024
#define NBLK 256          // B_ROWS / TPB, 1 row/thread; 1 block per CU
#define NGRP 16           // barrier groups of 16 blocks
#define PADW 32           // 32 dwords = 128 B padding per line

// per-layer padded regions (dwords)
#define PART_L_DW (NBLK * PADW)          // 256 block-partial lines
#define PART_TOT  (9 * PART_L_DW)
#define GGRP_L_DW (NGRP * PADW)          // 16 group lines
#define GGRP_TOT  (9 * GGRP_L_DW)
#define STATS_TOT (9 * PADW)             // 21 derived floats per layer

// bar layout (dwords): root @0 | gcnt[g] @32+g*32 | gflag[g] @32+512+g*32
#define GC_OFF   32
#define GF_OFF   (32 + NGRP * PADW)
#define BAR_DWORDS (GF_OFF + NGRP * PADW)

typedef _Float16 f16;
typedef __attribute__((ext_vector_type(2))) __fp16 fp16x2_t;  // cvt_pkrtz return type
typedef __attribute__((ext_vector_type(8))) _Float16 f16x8;
typedef __attribute__((ext_vector_type(4))) float f32x4;
typedef __attribute__((ext_vector_type(16))) float f32x16;
typedef __attribute__((ext_vector_type(2))) unsigned u32x2;

__device__ __forceinline__ float fast_tanh(float x) {
    float e = __expf(2.0f * x);
    return 1.0f - 2.0f * __builtin_amdgcn_rcpf(e + 1.0f);
}
__device__ __forceinline__ float pkh(float a, float b) {
    fp16x2_t h = __builtin_amdgcn_cvt_pkrtz(a, b);
    return __builtin_bit_cast(float, h);
}
__device__ __forceinline__ f16x8 mk8(float a, float b, float c, float d) {
    f32x4 v = {a, b, c, d};
    return __builtin_bit_cast(f16x8, v);
}
__device__ __forceinline__ float bcf(unsigned u) { return __builtin_bit_cast(float, u); }
__device__ __forceinline__ u32x2 pls(float a, float b) {
    return __builtin_amdgcn_permlane32_swap(
        __builtin_bit_cast(unsigned, a), __builtin_bit_cast(unsigned, b),
        false, false);
}

#define ACC16(pp) do {                                                      \
    float4 v0 = (pp)[0], v1 = (pp)[1], v2 = (pp)[2], v3 = (pp)[3];          \
    s[0]+=v0.x; s[1]+=v0.y; s[2]+=v0.z;  s[3]+=v0.w;                        \
    s[4]+=v1.x; s[5]+=v1.y; s[6]+=v1.z;  s[7]+=v1.w;                        \
    s[8]+=v2.x; s[9]+=v2.y; s[10]+=v2.z; s[11]+=v2.w;                       \
    s[12]+=v3.x; s[13]+=v3.y; s[14]+=v3.z; s[15]+=v3.w;                     \
} while (0)

// Barrier + in-tree stats aggregation. Group-last sums its 16 block lines,
// root-last sums 16 group lines + computes derived stats, then releases flags.
__device__ __forceinline__ void gbar_stats(
    float* part, float* ggrp, float* stats, unsigned* bar,
    unsigned target, int Lx,
    const float* logs, const float* bvec, const float* log_gamma)
{
    __syncthreads();
    if (threadIdx.x == 0) {
        const int g = blockIdx.x >> 4;
        unsigned old = __hip_atomic_fetch_add(bar + GC_OFF + g * PADW, 1u,
                                              __ATOMIC_ACQ_REL,
                                              __HIP_MEMORY_SCOPE_AGENT);
        if (old + 1 == target * (NBLK / NGRP)) {          // last in group
            float s[16];
            #pragma unroll
            for (int j = 0; j < 16; ++j) s[j] = 0.f;
            const float* pb = part + (size_t)Lx * PART_L_DW + (size_t)(g * 16) * PADW;
            #pragma unroll
            for (int b = 0; b < 16; ++b) {
                const float4* pp = reinterpret_cast<const float4*>(pb + b * PADW);
                ACC16(pp);
            }
            float* gg = ggrp + (size_t)Lx * GGRP_L_DW + (size_t)g * PADW;
            #pragma unroll
            for (int j = 0; j < 16; ++j)
                __hip_atomic_store(gg + j, s[j], __ATOMIC_RELAXED,
                                   __HIP_MEMORY_SCOPE_AGENT);
            unsigned ro = __hip_atomic_fetch_add(bar, 1u, __ATOMIC_ACQ_REL,
                                                 __HIP_MEMORY_SCOPE_AGENT);
            if (ro + 1 == target * NGRP) {                // last overall
                float s[16];
                #pragma unroll
                for (int j = 0; j < 16; ++j) s[j] = 0.f;
                const float* gb = ggrp + (size_t)Lx * GGRP_L_DW;
                #pragma unroll
                for (int q = 0; q < NGRP; ++q) {
                    const float4* pp = reinterpret_cast<const float4*>(gb + q * PADW);
                    ACC16(pp);
                }
                const float invB = 1.0f / (float)B_ROWS;
                float lv[21];
                float ss = 0.f;
                #pragma unroll
                for (int j = 0; j < 8; ++j) {
                    float m = s[j] * invB;
                    float q = s[8 + j] * invB;
                    float v = q - m * m;
                    v = v < 0.f ? 0.f : v;
                    float li = -(1.0f / 3.0f) * __logf(sqrtf(v) + 1e-6f);
                    float sv = logs[Lx * 8 + j] + li;
                    sv = sv < -5.f ? -5.f : (sv > 5.f ? 5.f : sv);
                    lv[j]     = __expf(sv);
                    lv[8 + j] = bvec[Lx * 8 + j] - m;
                    ss += sv;
                }
                #pragma unroll
                for (int j = 0; j < 4; ++j) {
                    float lg = log_gamma[Lx * 4 + j];
                    lg = lg < -5.f ? -5.f : (lg > 5.f ? 5.f : lg);
                    lv[16 + j] = __expf(lg);
                }
                lv[20] = ss;
                float* st = stats + (size_t)Lx * PADW;
                #pragma unroll
                for (int j = 0; j < 21; ++j)
                    __hip_atomic_store(st + j, lv[j], __ATOMIC_RELAXED,
                                       __HIP_MEMORY_SCOPE_AGENT);
                #pragma unroll
                for (int i = 0; i < NGRP; ++i)
                    __hip_atomic_store(bar + GF_OFF + i * PADW, target,
                                       __ATOMIC_RELEASE,
                                       __HIP_MEMORY_SCOPE_AGENT);
            }
        }
        unsigned* gf = bar + GF_OFF + g * PADW;
        while (__hip_atomic_load(gf, __ATOMIC_RELAXED,
                                 __HIP_MEMORY_SCOPE_AGENT) < target)
            __builtin_amdgcn_s_sleep(2);
        (void)__hip_atomic_load(gf, __ATOMIC_ACQUIRE, __HIP_MEMORY_SCOPE_AGENT);
    }
    __syncthreads();
}

// ---------------------------------------------------------------------------
// Setup: pack W1 / W2 / Wf into MFMA A-fragment order, f16; zero bar region.
// ---------------------------------------------------------------------------
#define PKBLK 80
__global__ void __launch_bounds__(256)
pack_weights(const float* __restrict__ W1, const float* __restrict__ W2,
             const float* __restrict__ Wf,
             f16* __restrict__ w1pk, f16* __restrict__ w2pk, f16* __restrict__ wfpk,
             unsigned* __restrict__ bar)
{
    int i = blockIdx.x * 256 + threadIdx.x;     // 0 .. 20479
    if (i < 16384) {
        int which = i >> 13;
        int t  = i & 8191;
        int j  = t & 7;
        int ln = (t >> 3) & 63;
        int kh = (t >> 9) & 1;
        int L  = t >> 10;
        int k  = kh * 16 + ((ln >> 5) << 3) + j;
        if (which == 0) {
            w2pk[t] = (f16)W2[L * 1024 + k * 32 + (ln & 31)];
        } else {
            int row = ln & 31;
            wfpk[t] = (row < 8) ? (f16)Wf[L * 256 + k * 8 + row] : (f16)0.f;
        }
    } else {
        int t  = i - 16384;                     // 0 .. 4095
        int j  = t & 7;
        int ln = (t >> 3) & 63;
        int L  = t >> 9;
        int k  = ((ln >> 5) << 3) + j;
        w1pk[t] = (k < 4) ? (f16)W1[L * 128 + k * 32 + (ln & 31)] : (f16)0.f;
    }
    if (i < BAR_DWORDS) bar[i] = 0u;            // reset barrier each launch
}

// ---------------------------------------------------------------------------
// Fused persistent kernel: all 8 layers; z, logdet in registers throughout.
// ---------------------------------------------------------------------------
__global__ void __launch_bounds__(TPB, 4)
flow_fused(const float* __restrict__ x,    const float* __restrict__ logdet,
           const float* __restrict__ bvec, const float* __restrict__ logs,
           const float* __restrict__ log_gamma,
           const float* __restrict__ b1,   const float* __restrict__ b2,
           const float* __restrict__ bf,
           const f16* __restrict__ w1pk,   const f16* __restrict__ w2pk,
           const f16* __restrict__ wfpk,
           float* __restrict__ out,
           float* part, float* ggrp, float* stats,
           unsigned* __restrict__ bar)
{
    const int tid  = threadIdx.x;
    const int bid  = blockIdx.x;
    const int lane = tid & 63;
    const int wid  = tid >> 6;          // 16 waves
    const bool lo  = lane < 32;
    // bit-reversed low-4 lane bits: component index after payload-halving butterfly
    const int br = ((lane & 1) << 3) | ((lane & 2) << 1) | ((lane & 4) >> 1) | ((lane & 8) >> 3);
    const size_t r0 = (size_t)bid * TPB + tid;

    __shared__ float lred[16 * 16];

    // ---- load row + logdet (persistent registers) ----
    float z[8];
    {
        const float4* p0 = reinterpret_cast<const float4*>(x + r0 * 8);
        float4 a = p0[0], c = p0[1];
        z[0]=a.x; z[1]=a.y; z[2]=a.z; z[3]=a.w;
        z[4]=c.x; z[5]=c.y; z[6]=c.z; z[7]=c.w;
    }
    float ldv = logdet[r0];

    // ---- initial partials of x -> part[0][bid] (payload-halving butterfly) ----
    {
        float acc[16];
        #pragma unroll
        for (int j = 0; j < 8; ++j) { acc[j] = z[j]; acc[8 + j] = z[j] * z[j]; }
        #pragma unroll
        for (int i = 0; i < 8; ++i) {
            float snd = (lane & 1) ? acc[i] : acc[8 + i];
            float kp  = (lane & 1) ? acc[8 + i] : acc[i];
            acc[i] = kp + __shfl_xor(snd, 1, 64);
        }
        #pragma unroll
        for (int i = 0; i < 4; ++i) {
            float snd = (lane & 2) ? acc[i] : acc[4 + i];
            float kp  = (lane & 2) ? acc[4 + i] : acc[i];
            acc[i] = kp + __shfl_xor(snd, 2, 64);
        }
        #pragma unroll
        for (int i = 0; i < 2; ++i) {
            float snd = (lane & 4) ? acc[i] : acc[2 + i];
            float kp  = (lane & 4) ? acc[2 + i] : acc[i];
            acc[i] = kp + __shfl_xor(snd, 4, 64);
        }
        {
            float snd = (lane & 8) ? acc[0] : acc[1];
            float kp  = (lane & 8) ? acc[1] : acc[0];
            acc[0] = kp + __shfl_xor(snd, 8, 64);
        }
        acc[0] += __shfl_xor(acc[0], 16, 64);
        acc[0] += __shfl_xor(acc[0], 32, 64);
        if (lane < 16) lred[wid * 16 + br] = acc[0];
        __syncthreads();
        if (tid < 16) {
            float s = 0.f;
            #pragma unroll
            for (int w = 0; w < 16; ++w) s += lred[w * 16 + tid];
            __hip_atomic_store(part + (size_t)bid * PADW + tid, s,
                               __ATOMIC_RELAXED, __HIP_MEMORY_SCOPE_AGENT);
        }
    }
    gbar_stats(part, ggrp, stats, bar, 1, 0, logs, bvec, log_gamma);

    const f16x8* w1p = reinterpret_cast<const f16x8*>(w1pk);
    const f16x8* w2p = reinterpret_cast<const f16x8*>(w2pk);
    const f16x8* wfp = reinterpret_cast<const f16x8*>(wfpk);

    #pragma unroll 1
    for (int L = 0; L < 8; ++L) {
        // hoist A-fragment loads
        const f16x8 W1A = w1p[L * 64 + lane];
        const f16x8 A0  = w2p[(L * 2 + 0) * 64 + lane];
        const f16x8 A1  = w2p[(L * 2 + 1) * 64 + lane];
        const f16x8 F0  = wfp[(L * 2 + 0) * 64 + lane];
        const f16x8 F1  = wfp[(L * 2 + 1) * 64 + lane];

        // ---- read 21 derived stats (computed in-barrier by the aggregator) ----
        float es[8], beta[8], gfac[4], sum_s;
        {
            const float* st = stats + (size_t)L * PADW;
            if (wid == 0 && lane < 21)
                lred[lane] = __hip_atomic_load(st + lane, __ATOMIC_RELAXED,
                                               __HIP_MEMORY_SCOPE_AGENT);
            __syncthreads();
            #pragma unroll
            for (int j = 0; j < 8; ++j) { es[j] = lred[j]; beta[j] = lred[8 + j]; }
            #pragma unroll
            for (int j = 0; j < 4; ++j) gfac[j] = lred[16 + j];
            sum_s = lred[20];
            __syncthreads();   // all reads done before lred reuse
        }

        // ---- actnorm ----
        #pragma unroll
        for (int j = 0; j < 8; ++j)
            z[j] = (z[j] + beta[j]) * es[j];

        const float* vb1 = b1 + L * 32;
        const float* vb2 = b2 + L * 32;
        const float* vbf = bf + L * 8;

        // ---- W1 via MFMA: h1^T = W1^T(padded K=16) @ z1^T ----
        float zp0 = pkh(z[0], z[1]);
        float zp1 = pkh(z[2], z[3]);
        u32x2 s0 = pls(zp0, 0.f);
        u32x2 s1 = pls(zp1, 0.f);
        f16x8 Z0 = mk8(bcf(s0[0]), bcf(s1[0]), 0.f, 0.f);   // rows 0-31
        f16x8 Z1 = mk8(bcf(s0[1]), bcf(s1[1]), 0.f, 0.f);   // rows 32-63

        f32x16 g0 = {}, g1 = {};
        g0 = __builtin_amdgcn_mfma_f32_32x32x16_f16(W1A, Z0, g0, 0, 0, 0);
        g1 = __builtin_amdgcn_mfma_f32_32x32x16_f16(W1A, Z1, g1, 0, 0, 0);

        // bias + relu + pack to f16 pairs
        float qg0[8], qg1[8];
        {
            float h0[16], h1v[16];
            #pragma unroll
            for (int r = 0; r < 16; ++r) {
                int wlo = (r & 3) + 8 * (r >> 2);
                float bsel = lo ? vb1[wlo] : vb1[wlo + 4];
                float a = g0[r] + bsel; h0[r]  = a > 0.f ? a : 0.f;
                float b = g1[r] + bsel; h1v[r] = b > 0.f ? b : 0.f;
            }
            #pragma unroll
            for (int c = 0; c < 8; ++c) {
                qg0[c] = pkh(h0[2 * c], h0[2 * c + 1]);
                qg1[c] = pkh(h1v[2 * c], h1v[2 * c + 1]);
            }
        }

        // ---- W2 B-frags via permlane32_swap ----
        u32x2 pA = pls(qg0[0], qg0[2]);
        u32x2 pB = pls(qg0[1], qg0[3]);
        u32x2 pC = pls(qg0[4], qg0[6]);
        u32x2 pD = pls(qg0[5], qg0[7]);
        f16x8 B00 = mk8(bcf(pA[0]), bcf(pB[0]), bcf(pA[1]), bcf(pB[1]));
        f16x8 B01 = mk8(bcf(pC[0]), bcf(pD[0]), bcf(pC[1]), bcf(pD[1]));
        pA = pls(qg1[0], qg1[2]);
        pB = pls(qg1[1], qg1[3]);
        pC = pls(qg1[4], qg1[6]);
        pD = pls(qg1[5], qg1[7]);
        f16x8 B10 = mk8(bcf(pA[0]), bcf(pB[0]), bcf(pA[1]), bcf(pB[1]));
        f16x8 B11 = mk8(bcf(pC[0]), bcf(pD[0]), bcf(pC[1]), bcf(pD[1]));

        f32x16 d0 = {}, d1 = {};
        d0 = __builtin_amdgcn_mfma_f32_32x32x16_f16(A0, B00, d0, 0, 0, 0);
        d0 = __builtin_amdgcn_mfma_f32_32x32x16_f16(A1, B01, d0, 0, 0, 0);
        d1 = __builtin_amdgcn_mfma_f32_32x32x16_f16(A0, B10, d1, 0, 0, 0);
        d1 = __builtin_amdgcn_mfma_f32_32x32x16_f16(A1, B11, d1, 0, 0, 0);

        // ---- + b2, relu, pack ----
        float P0[8], P1[8];
        {
            float h2g0[16], h2g1[16];
            #pragma unroll
            for (int r = 0; r < 16; ++r) {
                int wlo = (r & 3) + 8 * (r >> 2);
                float bsel = lo ? vb2[wlo] : vb2[wlo + 4];
                float a = d0[r] + bsel; h2g0[r] = a > 0.f ? a : 0.f;
                float b = d1[r] + bsel; h2g1[r] = b > 0.f ? b : 0.f;
            }
            #pragma unroll
            for (int c = 0; c < 8; ++c) {
                P0[c] = pkh(h2g0[2 * c], h2g0[2 * c + 1]);
                P1[c] = pkh(h2g1[2 * c], h2g1[2 * c + 1]);
            }
        }

        // ---- Wf C-frags via permlane32_swap ----
        u32x2 pE = pls(P0[0], P0[2]);
        u32x2 pF = pls(P0[1], P0[3]);
        u32x2 pG = pls(P0[4], P0[6]);
        u32x2 pH = pls(P0[5], P0[7]);
        f16x8 C00 = mk8(bcf(pE[0]), bcf(pF[0]), bcf(pE[1]), bcf(pF[1]));
        f16x8 C01 = mk8(bcf(pG[0]), bcf(pH[0]), bcf(pG[1]), bcf(pH[1]));
        pE = pls(P1[0], P1[2]);
        pF = pls(P1[1], P1[3]);
        pG = pls(P1[4], P1[6]);
        pH = pls(P1[5], P1[7]);
        f16x8 C10 = mk8(bcf(pE[0]), bcf(pF[0]), bcf(pE[1]), bcf(pF[1]));
        f16x8 C11 = mk8(bcf(pG[0]), bcf(pH[0]), bcf(pG[1]), bcf(pH[1]));

        f32x16 e0 = {}, e1 = {};
        e0 = __builtin_amdgcn_mfma_f32_32x32x16_f16(F0, C00, e0, 0, 0, 0);
        e0 = __builtin_amdgcn_mfma_f32_32x32x16_f16(F1, C01, e0, 0, 0, 0);
        e1 = __builtin_amdgcn_mfma_f32_32x32x16_f16(F0, C10, e1, 0, 0, 0);
        e1 = __builtin_amdgcn_mfma_f32_32x32x16_f16(F1, C11, e1, 0, 0, 0);

        // ---- gather own row's h3 via permlane32_swap ----
        float h3[8];
        #pragma unroll
        for (int r = 0; r < 4; ++r) {
            u32x2 pe = pls(e0[r], e1[r]);
            h3[r]     = bcf(pe[0]) + vbf[r];
            h3[r + 4] = bcf(pe[1]) + vbf[r + 4];
        }

        // ---- coupling epilogue + permutation + next-layer partials ----
        float nacc[16];
        {
            float ldl = 0.f;
            float nz[8];
            #pragma unroll
            for (int j = 0; j < 4; ++j) {
                float sc = 0.6f * fast_tanh(h3[2 * j + 1]);
                float sh = gfac[j] * fast_tanh(h3[2 * j]);
                float z2 = z[4 + j];
                z2 = z2 + sc * z2 + sh;
                ldl += __logf(1.0f + sc);
                nz[3 - j] = z2;      // reversed: out[3-j] = z2_j
                nz[7 - j] = z[j];    // reversed: out[7-j] = z1_j
            }
            ldv += sum_s + ldl;
            #pragma unroll
            for (int j = 0; j < 8; ++j) {
                z[j] = nz[j];
                nacc[j]     = nz[j];
                nacc[8 + j] = nz[j] * nz[j];
            }
        }

        if (L < 7) {
            #pragma unroll
            for (int i = 0; i < 8; ++i) {
                float snd = (lane & 1) ? nacc[i] : nacc[8 + i];
                float kp  = (lane & 1) ? nacc[8 + i] : nacc[i];
                nacc[i] = kp + __shfl_xor(snd, 1, 64);
            }
            #pragma unroll
            for (int i = 0; i < 4; ++i) {
                float snd = (lane & 2) ? nacc[i] : nacc[4 + i];
                float kp  = (lane & 2) ? nacc[4 + i] : nacc[i];
                nacc[i] = kp + __shfl_xor(snd, 2, 64);
            }
            #pragma unroll
            for (int i = 0; i < 2; ++i) {
                float snd = (lane & 4) ? nacc[i] : nacc[2 + i];
                float kp  = (lane & 4) ? nacc[2 + i] : nacc[i];
                nacc[i] = kp + __shfl_xor(snd, 4, 64);
            }
            {
                float snd = (lane & 8) ? nacc[0] : nacc[1];
                float kp  = (lane & 8) ? nacc[1] : nacc[0];
                nacc[0] = kp + __shfl_xor(snd, 8, 64);
            }
            nacc[0] += __shfl_xor(nacc[0], 16, 64);
            nacc[0] += __shfl_xor(nacc[0], 32, 64);
            if (lane < 16) lred[wid * 16 + br] = nacc[0];
            __syncthreads();
            if (tid < 16) {
                float s = 0.f;
                #pragma unroll
                for (int w = 0; w < 16; ++w) s += lred[w * 16 + tid];
                __hip_atomic_store(part + (size_t)(L + 1) * PART_L_DW +
                                       (size_t)bid * PADW + tid, s,
                                   __ATOMIC_RELAXED, __HIP_MEMORY_SCOPE_AGENT);
            }
            gbar_stats(part, ggrp, stats, bar, (unsigned)(L + 2), L + 1,
                       logs, bvec, log_gamma);
        }
    }

    // ---- store outputs: z (B,8) then ld (B,1) ----
    {
        float4* p0 = reinterpret_cast<float4*>(out + r0 * 8);
        float4 a, c;
        a.x=z[0]; a.y=z[1]; a.z=z[2]; a.w=z[3];
        c.x=z[4]; c.y=z[5]; c.z=z[6]; c.w=z[7];
        p0[0] = a; p0[1] = c;
    }
    out[(size_t)B_ROWS * 8 + r0] = ldv;
}

extern "C" void kernel_launch(void* const* d_in, const int* in_sizes, int n_in,
                              void* d_out, int out_size, void* d_ws, size_t ws_size,
                              hipStream_t stream) {
    const float* x      = (const float*)d_in[0];
    const float* logdet = (const float*)d_in[1];
    const float* bvec   = (const float*)d_in[2];
    const float* logs   = (const float*)d_in[3];
    const float* lg     = (const float*)d_in[4];
    const float* W1     = (const float*)d_in[5];
    const float* b1     = (const float*)d_in[6];
    const float* W2     = (const float*)d_in[7];
    const float* b2     = (const float*)d_in[8];
    const float* Wf     = (const float*)d_in[9];
    const float* bf     = (const float*)d_in[10];
    float* out = (float*)d_out;

    // ws layout: w1pk[8KB] | w2pk[16KB] | wfpk[16KB]
    //            | part[PART_TOT f32] | ggrp[GGRP_TOT] | stats[STATS_TOT]
    //            | bar[BAR_DWORDS u32]
    f16*      w1pk  = (f16*)d_ws;
    f16*      w2pk  = w1pk + 4096;
    f16*      wfpk  = w2pk + 8192;
    float*    part  = (float*)(wfpk + 8192);
    float*    ggrp  = part + PART_TOT;
    float*    stats = ggrp + GGRP_TOT;
    unsigned* bar   = (unsigned*)(stats + STATS_TOT);

    pack_weights<<<PKBLK, 256, 0, stream>>>(W1, W2, Wf, w1pk, w2pk, wfpk, bar);

    void* args[] = {&x, &logdet, &bvec, &logs, &lg, &b1, &b2, &bf,
                    &w1pk, &w2pk, &wfpk, &out, &part, &ggrp, &stats, &bar};
    hipLaunchKernel(reinterpret_cast<void*>(&flow_fused),
                    dim3(NBLK), dim3(TPB), args, 0, stream);
}

// Round 13
// 112.184 us; speedup vs baseline: 1.6909x; 1.6909x over previous
//
#include <hip/hip_runtime.h>

#define B_ROWS 262144
#define TPB 1024
#define NBLK 256          // B_ROWS / TPB, 1 row/thread; 1 block per CU
#define NGRP 16           // barrier groups of 16 blocks
#define PADW 32           // 32 dwords = 128 B padding per sync line

// slots: [9 layers][16 stats][64 slots] floats, unpadded (R10-proven contention)
#define SLOT_L_DW (16 * 64)
#define SLOTS_TOT (9 * SLOT_L_DW)
// stats: [9 layers][32] (21 used), one 128B line per layer
#define STATS_L_DW 32
#define STATS_TOT (9 * STATS_L_DW)

// bar layout (dwords): root @0 | gcnt[g] @32+g*32 | gflag[g] @32+512+g*32
#define GC_OFF   32
#define GF_OFF   (32 + NGRP * PADW)
#define BAR_DWORDS (GF_OFF + NGRP * PADW)

typedef _Float16 f16;
typedef __attribute__((ext_vector_type(2))) __fp16 fp16x2_t;  // cvt_pkrtz return type
typedef __attribute__((ext_vector_type(8))) _Float16 f16x8;
typedef __attribute__((ext_vector_type(4))) float f32x4;
typedef __attribute__((ext_vector_type(16))) float f32x16;
typedef __attribute__((ext_vector_type(2))) unsigned u32x2;

__device__ __forceinline__ float fast_tanh(float x) {
    float e = __expf(2.0f * x);
    return 1.0f - 2.0f * __builtin_amdgcn_rcpf(e + 1.0f);
}
__device__ __forceinline__ float pkh(float a, float b) {
    fp16x2_t h = __builtin_amdgcn_cvt_pkrtz(a, b);
    return __builtin_bit_cast(float, h);
}
__device__ __forceinline__ f16x8 mk8(float a, float b, float c, float d) {
    f32x4 v = {a, b, c, d};
    return __builtin_bit_cast(f16x8, v);
}
__device__ __forceinline__ float bcf(unsigned u) { return __builtin_bit_cast(float, u); }
__device__ __forceinline__ u32x2 pls(float a, float b) {
    return __builtin_amdgcn_permlane32_swap(
        __builtin_bit_cast(unsigned, a), __builtin_bit_cast(unsigned, b),
        false, false);
}

// ---------------------------------------------------------------------------
// Barrier + designated-aggregator stats. Arrival tree: group counters -> root.
// Block 0 wave 0 polls root, reads slots ONCE (64-lane parallel), computes the
// 21 derived stats lane-parallel, stores them, releases group flags.
// Other blocks spin on their group flag, then read 21 floats.
// lred[0..20] holds the derived stats for the layer on exit.
// ---------------------------------------------------------------------------
__device__ __forceinline__ void gbar_stats(
    float* slots, float* stats, unsigned* bar, unsigned target, int Lx,
    const float* logs, const float* bvec, const float* lgam, float* lred)
{
    const int tid  = threadIdx.x;
    const int lane = tid & 63;
    const int wid  = tid >> 6;
    const int bid  = blockIdx.x;
    __syncthreads();
    if (wid == 0) {
        if (lane == 0) {
            const int g = bid >> 4;
            unsigned old = __hip_atomic_fetch_add(bar + GC_OFF + g * PADW, 1u,
                                                  __ATOMIC_ACQ_REL,
                                                  __HIP_MEMORY_SCOPE_AGENT);
            if (old + 1 == target * (NBLK / NGRP))
                __hip_atomic_fetch_add(bar, 1u, __ATOMIC_ACQ_REL,
                                       __HIP_MEMORY_SCOPE_AGENT);
        }
        if (bid == 0) {
            // aggregator: wait for all groups
            while (__hip_atomic_load(bar, __ATOMIC_RELAXED,
                                     __HIP_MEMORY_SCOPE_AGENT) < target * NGRP)
                __builtin_amdgcn_s_sleep(2);
            (void)__hip_atomic_load(bar, __ATOMIC_ACQUIRE,
                                    __HIP_MEMORY_SCOPE_AGENT);
            const float* sl = slots + (size_t)Lx * SLOT_L_DW;
            float a16[16];
            #pragma unroll
            for (int j = 0; j < 16; ++j)
                a16[j] = __hip_atomic_load(sl + j * 64 + lane, __ATOMIC_RELAXED,
                                           __HIP_MEMORY_SCOPE_AGENT);
            #pragma unroll
            for (int d = 1; d < 64; d <<= 1) {
                #pragma unroll
                for (int j = 0; j < 16; ++j) a16[j] += __shfl_xor(a16[j], d, 64);
            }
            // derived stats, lane-parallel
            const float invB = 1.0f / (float)B_ROWS;
            float lv0 = 0.f, lv1 = 0.f, sl8 = 0.f, gf = 0.f;
            if (lane < 8) {
                float m = a16[lane] * invB;
                float q = a16[8 + lane] * invB;
                float v = q - m * m;
                v = v < 0.f ? 0.f : v;
                float li = -(1.0f / 3.0f) * __logf(sqrtf(v) + 1e-6f);
                float s = logs[Lx * 8 + lane] + li;
                s = s < -5.f ? -5.f : (s > 5.f ? 5.f : s);
                lv0 = __expf(s);
                lv1 = bvec[Lx * 8 + lane] - m;
                sl8 = s;
            } else if (lane < 12) {
                float lg = lgam[Lx * 4 + (lane - 8)];
                lg = lg < -5.f ? -5.f : (lg > 5.f ? 5.f : lg);
                gf = __expf(lg);
            }
            // sum_s over lanes 0..7 (xor within 8-lane group)
            float ss = sl8;
            ss += __shfl_xor(ss, 1, 64);
            ss += __shfl_xor(ss, 2, 64);
            ss += __shfl_xor(ss, 4, 64);
            float* st = stats + (size_t)Lx * STATS_L_DW;
            if (lane < 8) {
                __hip_atomic_store(st + lane, lv0, __ATOMIC_RELAXED,
                                   __HIP_MEMORY_SCOPE_AGENT);
                __hip_atomic_store(st + 8 + lane, lv1, __ATOMIC_RELAXED,
                                   __HIP_MEMORY_SCOPE_AGENT);
                lred[lane] = lv0; lred[8 + lane] = lv1;
            } else if (lane < 12) {
                __hip_atomic_store(st + 8 + lane, gf, __ATOMIC_RELAXED,
                                   __HIP_MEMORY_SCOPE_AGENT);   // st[16+(lane-8)]
                lred[8 + lane] = gf;
            }
            if (lane == 0) {
                __hip_atomic_store(st + 20, ss, __ATOMIC_RELAXED,
                                   __HIP_MEMORY_SCOPE_AGENT);
                lred[20] = ss;
            }
            // release: wave-level vmcnt orders the stats stores before flags
            if (lane < NGRP)
                __hip_atomic_store(bar + GF_OFF + lane * PADW, target,
                                   __ATOMIC_RELEASE, __HIP_MEMORY_SCOPE_AGENT);
        } else {
            const int g = bid >> 4;
            unsigned* gfp = bar + GF_OFF + g * PADW;
            while (__hip_atomic_load(gfp, __ATOMIC_RELAXED,
                                     __HIP_MEMORY_SCOPE_AGENT) < target)
                __builtin_amdgcn_s_sleep(2);
            (void)__hip_atomic_load(gfp, __ATOMIC_ACQUIRE,
                                    __HIP_MEMORY_SCOPE_AGENT);
            if (lane < 21)
                lred[lane] = __hip_atomic_load(stats + (size_t)Lx * STATS_L_DW + lane,
                                               __ATOMIC_RELAXED,
                                               __HIP_MEMORY_SCOPE_AGENT);
        }
    }
    __syncthreads();
}

// ---------------------------------------------------------------------------
// Setup: pack W1 / W2 / Wf into MFMA A-fragment order, f16; zero slots + bar.
// ---------------------------------------------------------------------------
#define PKBLK 80
__global__ void __launch_bounds__(256)
pack_weights(const float* __restrict__ W1, const float* __restrict__ W2,
             const float* __restrict__ Wf,
             f16* __restrict__ w1pk, f16* __restrict__ w2pk, f16* __restrict__ wfpk,
             float* __restrict__ slots, unsigned* __restrict__ bar)
{
    int i = blockIdx.x * 256 + threadIdx.x;     // 0 .. 20479
    if (i < 16384) {
        int which = i >> 13;
        int t  = i & 8191;
        int j  = t & 7;
        int ln = (t >> 3) & 63;
        int kh = (t >> 9) & 1;
        int L  = t >> 10;
        int k  = kh * 16 + ((ln >> 5) << 3) + j;
        if (which == 0) {
            w2pk[t] = (f16)W2[L * 1024 + k * 32 + (ln & 31)];
        } else {
            int row = ln & 31;
            wfpk[t] = (row < 8) ? (f16)Wf[L * 256 + k * 8 + row] : (f16)0.f;
        }
    } else {
        int t  = i - 16384;                     // 0 .. 4095
        int j  = t & 7;
        int ln = (t >> 3) & 63;
        int L  = t >> 9;
        int k  = ((ln >> 5) << 3) + j;
        w1pk[t] = (k < 4) ? (f16)W1[L * 128 + k * 32 + (ln & 31)] : (f16)0.f;
    }
    // zero slots (accumulators) + bar each launch
    if (i < SLOTS_TOT) slots[i] = 0.f;
    if (i < BAR_DWORDS) bar[i] = 0u;
}

// ---------------------------------------------------------------------------
// Fused persistent kernel: all 8 layers; z, logdet in registers throughout.
// ---------------------------------------------------------------------------
__global__ void __launch_bounds__(TPB, 4)
flow_fused(const float* __restrict__ x,    const float* __restrict__ logdet,
           const float* __restrict__ bvec, const float* __restrict__ logs,
           const float* __restrict__ log_gamma,
           const float* __restrict__ b1,   const float* __restrict__ b2,
           const float* __restrict__ bf,
           const f16* __restrict__ w1pk,   const f16* __restrict__ w2pk,
           const f16* __restrict__ wfpk,
           float* __restrict__ out,
           float* slots, float* stats, unsigned* __restrict__ bar)
{
    const int tid  = threadIdx.x;
    const int bid  = blockIdx.x;
    const int lane = tid & 63;
    const int wid  = tid >> 6;          // 16 waves
    const bool lo  = lane < 32;
    const int slot = bid & 63;
    // bit-reversed low-4 lane bits: component index after payload-halving butterfly
    const int br = ((lane & 1) << 3) | ((lane & 2) << 1) | ((lane & 4) >> 1) | ((lane & 8) >> 3);
    const size_t r0 = (size_t)bid * TPB + tid;

    __shared__ float lred[16 * 16];

    // ---- load row + logdet (persistent registers) ----
    float z[8];
    {
        const float4* p0 = reinterpret_cast<const float4*>(x + r0 * 8);
        float4 a = p0[0], c = p0[1];
        z[0]=a.x; z[1]=a.y; z[2]=a.z; z[3]=a.w;
        z[4]=c.x; z[5]=c.y; z[6]=c.z; z[7]=c.w;
    }
    float ldv = logdet[r0];

    // ---- initial partials of x -> slots[0] (payload-halving butterfly) ----
    {
        float acc[16];
        #pragma unroll
        for (int j = 0; j < 8; ++j) { acc[j] = z[j]; acc[8 + j] = z[j] * z[j]; }
        #pragma unroll
        for (int i = 0; i < 8; ++i) {
            float snd = (lane & 1) ? acc[i] : acc[8 + i];
            float kp  = (lane & 1) ? acc[8 + i] : acc[i];
            acc[i] = kp + __shfl_xor(snd, 1, 64);
        }
        #pragma unroll
        for (int i = 0; i < 4; ++i) {
            float snd = (lane & 2) ? acc[i] : acc[4 + i];
            float kp  = (lane & 2) ? acc[4 + i] : acc[i];
            acc[i] = kp + __shfl_xor(snd, 2, 64);
        }
        #pragma unroll
        for (int i = 0; i < 2; ++i) {
            float snd = (lane & 4) ? acc[i] : acc[2 + i];
            float kp  = (lane & 4) ? acc[2 + i] : acc[i];
            acc[i] = kp + __shfl_xor(snd, 4, 64);
        }
        {
            float snd = (lane & 8) ? acc[0] : acc[1];
            float kp  = (lane & 8) ? acc[1] : acc[0];
            acc[0] = kp + __shfl_xor(snd, 8, 64);
        }
        acc[0] += __shfl_xor(acc[0], 16, 64);
        acc[0] += __shfl_xor(acc[0], 32, 64);
        if (lane < 16) lred[wid * 16 + br] = acc[0];
        __syncthreads();
        if (tid < 16) {
            float s = 0.f;
            #pragma unroll
            for (int w = 0; w < 16; ++w) s += lred[w * 16 + tid];
            __hip_atomic_fetch_add(slots + tid * 64 + slot, s,
                                   __ATOMIC_RELAXED, __HIP_MEMORY_SCOPE_AGENT);
        }
    }
    gbar_stats(slots, stats, bar, 1, 0, logs, bvec, log_gamma, lred);

    const f16x8* w1p = reinterpret_cast<const f16x8*>(w1pk);
    const f16x8* w2p = reinterpret_cast<const f16x8*>(w2pk);
    const f16x8* wfp = reinterpret_cast<const f16x8*>(wfpk);

    #pragma unroll 1
    for (int L = 0; L < 8; ++L) {
        // hoist A-fragment loads
        const f16x8 W1A = w1p[L * 64 + lane];
        const f16x8 A0  = w2p[(L * 2 + 0) * 64 + lane];
        const f16x8 A1  = w2p[(L * 2 + 1) * 64 + lane];
        const f16x8 F0  = wfp[(L * 2 + 0) * 64 + lane];
        const f16x8 F1  = wfp[(L * 2 + 1) * 64 + lane];

        // ---- stats already in lred (filled by gbar_stats) ----
        float es[8], beta[8], gfac[4], sum_s;
        #pragma unroll
        for (int j = 0; j < 8; ++j) { es[j] = lred[j]; beta[j] = lred[8 + j]; }
        #pragma unroll
        for (int j = 0; j < 4; ++j) gfac[j] = lred[16 + j];
        sum_s = lred[20];
        __syncthreads();   // all reads done before lred reuse in epilogue

        // ---- actnorm ----
        #pragma unroll
        for (int j = 0; j < 8; ++j)
            z[j] = (z[j] + beta[j]) * es[j];

        const float* vb1 = b1 + L * 32;
        const float* vb2 = b2 + L * 32;
        const float* vbf = bf + L * 8;

        // ---- W1 via MFMA: h1^T = W1^T(padded K=16) @ z1^T ----
        float zp0 = pkh(z[0], z[1]);
        float zp1 = pkh(z[2], z[3]);
        u32x2 s0 = pls(zp0, 0.f);
        u32x2 s1 = pls(zp1, 0.f);
        f16x8 Z0 = mk8(bcf(s0[0]), bcf(s1[0]), 0.f, 0.f);   // rows 0-31
        f16x8 Z1 = mk8(bcf(s0[1]), bcf(s1[1]), 0.f, 0.f);   // rows 32-63

        f32x16 g0 = {}, g1 = {};
        g0 = __builtin_amdgcn_mfma_f32_32x32x16_f16(W1A, Z0, g0, 0, 0, 0);
        g1 = __builtin_amdgcn_mfma_f32_32x32x16_f16(W1A, Z1, g1, 0, 0, 0);

        // bias + relu + pack to f16 pairs
        float qg0[8], qg1[8];
        {
            float h0[16], h1v[16];
            #pragma unroll
            for (int r = 0; r < 16; ++r) {
                int wlo = (r & 3) + 8 * (r >> 2);
                float bsel = lo ? vb1[wlo] : vb1[wlo + 4];
                float a = g0[r] + bsel; h0[r]  = a > 0.f ? a : 0.f;
                float b = g1[r] + bsel; h1v[r] = b > 0.f ? b : 0.f;
            }
            #pragma unroll
            for (int c = 0; c < 8; ++c) {
                qg0[c] = pkh(h0[2 * c], h0[2 * c + 1]);
                qg1[c] = pkh(h1v[2 * c], h1v[2 * c + 1]);
            }
        }

        // ---- W2 B-frags via permlane32_swap ----
        u32x2 pA = pls(qg0[0], qg0[2]);
        u32x2 pB = pls(qg0[1], qg0[3]);
        u32x2 pC = pls(qg0[4], qg0[6]);
        u32x2 pD = pls(qg0[5], qg0[7]);
        f16x8 B00 = mk8(bcf(pA[0]), bcf(pB[0]), bcf(pA[1]), bcf(pB[1]));
        f16x8 B01 = mk8(bcf(pC[0]), bcf(pD[0]), bcf(pC[1]), bcf(pD[1]));
        pA = pls(qg1[0], qg1[2]);
        pB = pls(qg1[1], qg1[3]);
        pC = pls(qg1[4], qg1[6]);
        pD = pls(qg1[5], qg1[7]);
        f16x8 B10 = mk8(bcf(pA[0]), bcf(pB[0]), bcf(pA[1]), bcf(pB[1]));
        f16x8 B11 = mk8(bcf(pC[0]), bcf(pD[0]), bcf(pC[1]), bcf(pD[1]));

        f32x16 d0 = {}, d1 = {};
        d0 = __builtin_amdgcn_mfma_f32_32x32x16_f16(A0, B00, d0, 0, 0, 0);
        d0 = __builtin_amdgcn_mfma_f32_32x32x16_f16(A1, B01, d0, 0, 0, 0);
        d1 = __builtin_amdgcn_mfma_f32_32x32x16_f16(A0, B10, d1, 0, 0, 0);
        d1 = __builtin_amdgcn_mfma_f32_32x32x16_f16(A1, B11, d1, 0, 0, 0);

        // ---- + b2, relu, pack ----
        float P0[8], P1[8];
        {
            float h2g0[16], h2g1[16];
            #pragma unroll
            for (int r = 0; r < 16; ++r) {
                int wlo = (r & 3) + 8 * (r >> 2);
                float bsel = lo ? vb2[wlo] : vb2[wlo + 4];
                float a = d0[r] + bsel; h2g0[r] = a > 0.f ? a : 0.f;
                float b = d1[r] + bsel; h2g1[r] = b > 0.f ? b : 0.f;
            }
            #pragma unroll
            for (int c = 0; c < 8; ++c) {
                P0[c] = pkh(h2g0[2 * c], h2g0[2 * c + 1]);
                P1[c] = pkh(h2g1[2 * c], h2g1[2 * c + 1]);
            }
        }

        // ---- Wf C-frags via permlane32_swap ----
        u32x2 pE = pls(P0[0], P0[2]);
        u32x2 pF = pls(P0[1], P0[3]);
        u32x2 pG = pls(P0[4], P0[6]);
        u32x2 pH = pls(P0[5], P0[7]);
        f16x8 C00 = mk8(bcf(pE[0]), bcf(pF[0]), bcf(pE[1]), bcf(pF[1]));
        f16x8 C01 = mk8(bcf(pG[0]), bcf(pH[0]), bcf(pG[1]), bcf(pH[1]));
        pE = pls(P1[0], P1[2]);
        pF = pls(P1[1], P1[3]);
        pG = pls(P1[4], P1[6]);
        pH = pls(P1[5], P1[7]);
        f16x8 C10 = mk8(bcf(pE[0]), bcf(pF[0]), bcf(pE[1]), bcf(pF[1]));
        f16x8 C11 = mk8(bcf(pG[0]), bcf(pH[0]), bcf(pG[1]), bcf(pH[1]));

        f32x16 e0 = {}, e1 = {};
        e0 = __builtin_amdgcn_mfma_f32_32x32x16_f16(F0, C00, e0, 0, 0, 0);
        e0 = __builtin_amdgcn_mfma_f32_32x32x16_f16(F1, C01, e0, 0, 0, 0);
        e1 = __builtin_amdgcn_mfma_f32_32x32x16_f16(F0, C10, e1, 0, 0, 0);
        e1 = __builtin_amdgcn_mfma_f32_32x32x16_f16(F1, C11, e1, 0, 0, 0);

        // ---- gather own row's h3 via permlane32_swap ----
        float h3[8];
        #pragma unroll
        for (int r = 0; r < 4; ++r) {
            u32x2 pe = pls(e0[r], e1[r]);
            h3[r]     = bcf(pe[0]) + vbf[r];
            h3[r + 4] = bcf(pe[1]) + vbf[r + 4];
        }

        // ---- coupling epilogue + permutation + next-layer partials ----
        float nacc[16];
        {
            float ldl = 0.f;
            float nz[8];
            #pragma unroll
            for (int j = 0; j < 4; ++j) {
                float sc = 0.6f * fast_tanh(h3[2 * j + 1]);
                float sh = gfac[j] * fast_tanh(h3[2 * j]);
                float z2 = z[4 + j];
                z2 = z2 + sc * z2 + sh;
                ldl += __logf(1.0f + sc);
                nz[3 - j] = z2;      // reversed: out[3-j] = z2_j
                nz[7 - j] = z[j];    // reversed: out[7-j] = z1_j
            }
            ldv += sum_s + ldl;
            #pragma unroll
            for (int j = 0; j < 8; ++j) {
                z[j] = nz[j];
                nacc[j]     = nz[j];
                nacc[8 + j] = nz[j] * nz[j];
            }
        }

        if (L < 7) {
            #pragma unroll
            for (int i = 0; i < 8; ++i) {
                float snd = (lane & 1) ? nacc[i] : nacc[8 + i];
                float kp  = (lane & 1) ? nacc[8 + i] : nacc[i];
                nacc[i] = kp + __shfl_xor(snd, 1, 64);
            }
            #pragma unroll
            for (int i = 0; i < 4; ++i) {
                float snd = (lane & 2) ? nacc[i] : nacc[4 + i];
                float kp  = (lane & 2) ? nacc[4 + i] : nacc[i];
                nacc[i] = kp + __shfl_xor(snd, 2, 64);
            }
            #pragma unroll
            for (int i = 0; i < 2; ++i) {
                float snd = (lane & 4) ? nacc[i] : nacc[2 + i];
                float kp  = (lane & 4) ? nacc[2 + i] : nacc[i];
                nacc[i] = kp + __shfl_xor(snd, 4, 64);
            }
            {
                float snd = (lane & 8) ? nacc[0] : nacc[1];
                float kp  = (lane & 8) ? nacc[1] : nacc[0];
                nacc[0] = kp + __shfl_xor(snd, 8, 64);
            }
            nacc[0] += __shfl_xor(nacc[0], 16, 64);
            nacc[0] += __shfl_xor(nacc[0], 32, 64);
            if (lane < 16) lred[wid * 16 + br] = nacc[0];
            __syncthreads();
            if (tid < 16) {
                float s = 0.f;
                #pragma unroll
                for (int w = 0; w < 16; ++w) s += lred[w * 16 + tid];
                __hip_atomic_fetch_add(slots + (size_t)(L + 1) * SLOT_L_DW +
                                           tid * 64 + slot, s,
                                       __ATOMIC_RELAXED, __HIP_MEMORY_SCOPE_AGENT);
            }
            gbar_stats(slots, stats, bar, (unsigned)(L + 2), L + 1,
                       logs, bvec, log_gamma, lred);
        }
    }

    // ---- store outputs: z (B,8) then ld (B,1) ----
    {
        float4* p0 = reinterpret_cast<float4*>(out + r0 * 8);
        float4 a, c;
        a.x=z[0]; a.y=z[1]; a.z=z[2]; a.w=z[3];
        c.x=z[4]; c.y=z[5]; c.z=z[6]; c.w=z[7];
        p0[0] = a; p0[1] = c;
    }
    out[(size_t)B_ROWS * 8 + r0] = ldv;
}

extern "C" void kernel_launch(void* const* d_in, const int* in_sizes, int n_in,
                              void* d_out, int out_size, void* d_ws, size_t ws_size,
                              hipStream_t stream) {
    const float* x      = (const float*)d_in[0];
    const float* logdet = (const float*)d_in[1];
    const float* bvec   = (const float*)d_in[2];
    const float* logs   = (const float*)d_in[3];
    const float* lg     = (const float*)d_in[4];
    const float* W1     = (const float*)d_in[5];
    const float* b1     = (const float*)d_in[6];
    const float* W2     = (const float*)d_in[7];
    const float* b2     = (const float*)d_in[8];
    const float* Wf     = (const float*)d_in[9];
    const float* bf     = (const float*)d_in[10];
    float* out = (float*)d_out;

    // ws layout: w1pk[8KB] | w2pk[16KB] | wfpk[16KB]
    //            | slots[SLOTS_TOT f32] | stats[STATS_TOT f32] | bar[BAR_DWORDS u32]
    f16*      w1pk  = (f16*)d_ws;
    f16*      w2pk  = w1pk + 4096;
    f16*      wfpk  = w2pk + 8192;
    float*    slots = (float*)(wfpk + 8192);
    float*    stats = slots + SLOTS_TOT;
    unsigned* bar   = (unsigned*)(stats + STATS_TOT);

    pack_weights<<<PKBLK, 256, 0, stream>>>(W1, W2, Wf, w1pk, w2pk, wfpk,
                                            slots, bar);

    void* args[] = {&x, &logdet, &bvec, &logs, &lg, &b1, &b2, &bf,
                    &w1pk, &w2pk, &wfpk, &out, &slots, &stats, &bar};
    hipLaunchKernel(reinterpret_cast<void*>(&flow_fused),
                    dim3(NBLK), dim3(TPB), args, 0, stream);
}

// Round 14
// 103.903 us; speedup vs baseline: 1.8257x; 1.0797x over previous
//
#include <hip/hip_runtime.h>

#define B_ROWS 262144
#define TPB 1024
#define NBLK 256          // B_ROWS / TPB, 1 row/thread; 1 block per CU
#define NGRP 64           // flat barrier: 64 groups of 4 blocks
#define PADW 32           // 32 dwords = 128 B padding per sync line

// slots: [9 layers][16 stats][64 slots] floats, unpadded
#define SLOT_L_DW (16 * 64)
#define SLOTS_TOT (9 * SLOT_L_DW)
// stats: [9 layers][32] (21 used), one 128B line per layer
#define STATS_L_DW 32
#define STATS_TOT (9 * STATS_L_DW)

// bar layout (dwords): gcnt[g] @g*32 | gflag[g] @GF_OFF+g*32
#define GF_OFF   (NGRP * PADW)
#define BAR_DWORDS (2 * NGRP * PADW)

typedef _Float16 f16;
typedef __attribute__((ext_vector_type(2))) __fp16 fp16x2_t;  // cvt_pkrtz return type
typedef __attribute__((ext_vector_type(8))) _Float16 f16x8;
typedef __attribute__((ext_vector_type(4))) float f32x4;
typedef __attribute__((ext_vector_type(16))) float f32x16;
typedef __attribute__((ext_vector_type(2))) unsigned u32x2;

__device__ __forceinline__ float fast_tanh(float x) {
    float e = __expf(2.0f * x);
    return 1.0f - 2.0f * __builtin_amdgcn_rcpf(e + 1.0f);
}
__device__ __forceinline__ float pkh(float a, float b) {
    fp16x2_t h = __builtin_amdgcn_cvt_pkrtz(a, b);
    return __builtin_bit_cast(float, h);
}
__device__ __forceinline__ f16x8 mk8(float a, float b, float c, float d) {
    f32x4 v = {a, b, c, d};
    return __builtin_bit_cast(f16x8, v);
}
__device__ __forceinline__ float bcf(unsigned u) { return __builtin_bit_cast(float, u); }
__device__ __forceinline__ u32x2 pls(float a, float b) {
    return __builtin_amdgcn_permlane32_swap(
        __builtin_bit_cast(unsigned, a), __builtin_bit_cast(unsigned, b),
        false, false);
}

// ---------------------------------------------------------------------------
// Flat barrier + designated-aggregator stats.
// Arrival: thread0 RMWs gcnt[bid>>2] (4 blocks/line). Block 0 wave 0 polls all
// 64 counters in parallel (lane g polls line g, __all ballot), one acquire
// fence, reads slots once, computes 21 derived stats, stores, releases 64
// flag lines in one wave-wide round. Others spin on their flag line.
// lred[0..20] holds the derived stats for the layer on exit.
// ---------------------------------------------------------------------------
__device__ __forceinline__ void gbar_stats(
    float* slots, float* stats, unsigned* bar, unsigned target, int Lx,
    const float* logs, const float* bvec, const float* lgam, float* lred)
{
    const int tid  = threadIdx.x;
    const int lane = tid & 63;
    const int wid  = tid >> 6;
    const int bid  = blockIdx.x;
    __syncthreads();
    if (wid == 0) {
        if (lane == 0)
            __hip_atomic_fetch_add(bar + (bid >> 2) * PADW, 1u,
                                   __ATOMIC_ACQ_REL, __HIP_MEMORY_SCOPE_AGENT);
        if (bid == 0) {
            // parallel detection: lane polls group counter `lane`
            const unsigned t4 = target * (NBLK / NGRP);
            while (true) {
                unsigned c = __hip_atomic_load(bar + lane * PADW, __ATOMIC_RELAXED,
                                               __HIP_MEMORY_SCOPE_AGENT);
                if (__all(c >= t4)) break;
                __builtin_amdgcn_s_sleep(1);
            }
            __threadfence();   // acquire: arrivals' released slot stores visible
            const float* sl = slots + (size_t)Lx * SLOT_L_DW;
            float a16[16];
            #pragma unroll
            for (int j = 0; j < 16; ++j)
                a16[j] = __hip_atomic_load(sl + j * 64 + lane, __ATOMIC_RELAXED,
                                           __HIP_MEMORY_SCOPE_AGENT);
            #pragma unroll
            for (int d = 1; d < 64; d <<= 1) {
                #pragma unroll
                for (int j = 0; j < 16; ++j) a16[j] += __shfl_xor(a16[j], d, 64);
            }
            // derived stats, lane-parallel
            const float invB = 1.0f / (float)B_ROWS;
            float lv0 = 0.f, lv1 = 0.f, sl8 = 0.f, gf = 0.f;
            if (lane < 8) {
                float m = a16[lane] * invB;
                float q = a16[8 + lane] * invB;
                float v = q - m * m;
                v = v < 0.f ? 0.f : v;
                float li = -(1.0f / 3.0f) * __logf(sqrtf(v) + 1e-6f);
                float s = logs[Lx * 8 + lane] + li;
                s = s < -5.f ? -5.f : (s > 5.f ? 5.f : s);
                lv0 = __expf(s);
                lv1 = bvec[Lx * 8 + lane] - m;
                sl8 = s;
            } else if (lane < 12) {
                float lg = lgam[Lx * 4 + (lane - 8)];
                lg = lg < -5.f ? -5.f : (lg > 5.f ? 5.f : lg);
                gf = __expf(lg);
            }
            float ss = sl8;
            ss += __shfl_xor(ss, 1, 64);
            ss += __shfl_xor(ss, 2, 64);
            ss += __shfl_xor(ss, 4, 64);
            float* st = stats + (size_t)Lx * STATS_L_DW;
            if (lane < 8) {
                __hip_atomic_store(st + lane, lv0, __ATOMIC_RELAXED,
                                   __HIP_MEMORY_SCOPE_AGENT);
                __hip_atomic_store(st + 8 + lane, lv1, __ATOMIC_RELAXED,
                                   __HIP_MEMORY_SCOPE_AGENT);
                lred[lane] = lv0; lred[8 + lane] = lv1;
            } else if (lane < 12) {
                __hip_atomic_store(st + 8 + lane, gf, __ATOMIC_RELAXED,
                                   __HIP_MEMORY_SCOPE_AGENT);   // st[16+(lane-8)]
                lred[8 + lane] = gf;
            }
            if (lane == 0) {
                __hip_atomic_store(st + 20, ss, __ATOMIC_RELAXED,
                                   __HIP_MEMORY_SCOPE_AGENT);
                lred[20] = ss;
            }
            // release flags: wave-wide vmcnt orders stats stores before flags
            __hip_atomic_store(bar + GF_OFF + lane * PADW, target,
                               __ATOMIC_RELEASE, __HIP_MEMORY_SCOPE_AGENT);
        } else {
            unsigned* gfp = bar + GF_OFF + (bid >> 2) * PADW;
            while (__hip_atomic_load(gfp, __ATOMIC_RELAXED,
                                     __HIP_MEMORY_SCOPE_AGENT) < target)
                __builtin_amdgcn_s_sleep(1);
            (void)__hip_atomic_load(gfp, __ATOMIC_ACQUIRE,
                                    __HIP_MEMORY_SCOPE_AGENT);
            if (lane < 21)
                lred[lane] = __hip_atomic_load(stats + (size_t)Lx * STATS_L_DW + lane,
                                               __ATOMIC_RELAXED,
                                               __HIP_MEMORY_SCOPE_AGENT);
        }
    }
    __syncthreads();
}

// ---------------------------------------------------------------------------
// Setup: pack W1 / W2 / Wf into MFMA A-fragment order, f16; zero slots + bar.
// ---------------------------------------------------------------------------
#define PKBLK 80
__global__ void __launch_bounds__(256)
pack_weights(const float* __restrict__ W1, const float* __restrict__ W2,
             const float* __restrict__ Wf,
             f16* __restrict__ w1pk, f16* __restrict__ w2pk, f16* __restrict__ wfpk,
             float* __restrict__ slots, unsigned* __restrict__ bar)
{
    int i = blockIdx.x * 256 + threadIdx.x;     // 0 .. 20479
    if (i < 16384) {
        int which = i >> 13;
        int t  = i & 8191;
        int j  = t & 7;
        int ln = (t >> 3) & 63;
        int kh = (t >> 9) & 1;
        int L  = t >> 10;
        int k  = kh * 16 + ((ln >> 5) << 3) + j;
        if (which == 0) {
            w2pk[t] = (f16)W2[L * 1024 + k * 32 + (ln & 31)];
        } else {
            int row = ln & 31;
            wfpk[t] = (row < 8) ? (f16)Wf[L * 256 + k * 8 + row] : (f16)0.f;
        }
    } else {
        int t  = i - 16384;                     // 0 .. 4095
        int j  = t & 7;
        int ln = (t >> 3) & 63;
        int L  = t >> 9;
        int k  = ((ln >> 5) << 3) + j;
        w1pk[t] = (k < 4) ? (f16)W1[L * 128 + k * 32 + (ln & 31)] : (f16)0.f;
    }
    // zero slots (accumulators) + bar each launch
    if (i < SLOTS_TOT) slots[i] = 0.f;
    if (i < BAR_DWORDS) bar[i] = 0u;
}

// ---------------------------------------------------------------------------
// Fused persistent kernel: all 8 layers; z, logdet in registers throughout.
// ---------------------------------------------------------------------------
__global__ void __launch_bounds__(TPB, 4)
flow_fused(const float* __restrict__ x,    const float* __restrict__ logdet,
           const float* __restrict__ bvec, const float* __restrict__ logs,
           const float* __restrict__ log_gamma,
           const float* __restrict__ b1,   const float* __restrict__ b2,
           const float* __restrict__ bf,
           const f16* __restrict__ w1pk,   const f16* __restrict__ w2pk,
           const f16* __restrict__ wfpk,
           float* __restrict__ out,
           float* slots, float* stats, unsigned* __restrict__ bar)
{
    const int tid  = threadIdx.x;
    const int bid  = blockIdx.x;
    const int lane = tid & 63;
    const int wid  = tid >> 6;          // 16 waves
    const bool lo  = lane < 32;
    const int slot = bid & 63;
    // bit-reversed low-4 lane bits: component index after payload-halving butterfly
    const int br = ((lane & 1) << 3) | ((lane & 2) << 1) | ((lane & 4) >> 1) | ((lane & 8) >> 3);
    const size_t r0 = (size_t)bid * TPB + tid;

    __shared__ float lred[16 * 16];

    // ---- load row + logdet (persistent registers) ----
    float z[8];
    {
        const float4* p0 = reinterpret_cast<const float4*>(x + r0 * 8);
        float4 a = p0[0], c = p0[1];
        z[0]=a.x; z[1]=a.y; z[2]=a.z; z[3]=a.w;
        z[4]=c.x; z[5]=c.y; z[6]=c.z; z[7]=c.w;
    }
    float ldv = logdet[r0];

    // ---- initial partials of x -> slots[0] (payload-halving butterfly) ----
    {
        float acc[16];
        #pragma unroll
        for (int j = 0; j < 8; ++j) { acc[j] = z[j]; acc[8 + j] = z[j] * z[j]; }
        #pragma unroll
        for (int i = 0; i < 8; ++i) {
            float snd = (lane & 1) ? acc[i] : acc[8 + i];
            float kp  = (lane & 1) ? acc[8 + i] : acc[i];
            acc[i] = kp + __shfl_xor(snd, 1, 64);
        }
        #pragma unroll
        for (int i = 0; i < 4; ++i) {
            float snd = (lane & 2) ? acc[i] : acc[4 + i];
            float kp  = (lane & 2) ? acc[4 + i] : acc[i];
            acc[i] = kp + __shfl_xor(snd, 2, 64);
        }
        #pragma unroll
        for (int i = 0; i < 2; ++i) {
            float snd = (lane & 4) ? acc[i] : acc[2 + i];
            float kp  = (lane & 4) ? acc[2 + i] : acc[i];
            acc[i] = kp + __shfl_xor(snd, 4, 64);
        }
        {
            float snd = (lane & 8) ? acc[0] : acc[1];
            float kp  = (lane & 8) ? acc[1] : acc[0];
            acc[0] = kp + __shfl_xor(snd, 8, 64);
        }
        acc[0] += __shfl_xor(acc[0], 16, 64);
        acc[0] += __shfl_xor(acc[0], 32, 64);
        if (lane < 16) lred[wid * 16 + br] = acc[0];
        __syncthreads();
        if (tid < 16) {
            float s = 0.f;
            #pragma unroll
            for (int w = 0; w < 16; ++w) s += lred[w * 16 + tid];
            __hip_atomic_fetch_add(slots + tid * 64 + slot, s,
                                   __ATOMIC_RELAXED, __HIP_MEMORY_SCOPE_AGENT);
        }
    }
    gbar_stats(slots, stats, bar, 1, 0, logs, bvec, log_gamma, lred);

    const f16x8* w1p = reinterpret_cast<const f16x8*>(w1pk);
    const f16x8* w2p = reinterpret_cast<const f16x8*>(w2pk);
    const f16x8* wfp = reinterpret_cast<const f16x8*>(wfpk);

    #pragma unroll 1
    for (int L = 0; L < 8; ++L) {
        // hoist A-fragment loads
        const f16x8 W1A = w1p[L * 64 + lane];
        const f16x8 A0  = w2p[(L * 2 + 0) * 64 + lane];
        const f16x8 A1  = w2p[(L * 2 + 1) * 64 + lane];
        const f16x8 F0  = wfp[(L * 2 + 0) * 64 + lane];
        const f16x8 F1  = wfp[(L * 2 + 1) * 64 + lane];

        // ---- stats already in lred (filled by gbar_stats) ----
        float es[8], beta[8], gfac[4], sum_s;
        #pragma unroll
        for (int j = 0; j < 8; ++j) { es[j] = lred[j]; beta[j] = lred[8 + j]; }
        #pragma unroll
        for (int j = 0; j < 4; ++j) gfac[j] = lred[16 + j];
        sum_s = lred[20];
        __syncthreads();   // all reads done before lred reuse in epilogue

        // ---- actnorm ----
        #pragma unroll
        for (int j = 0; j < 8; ++j)
            z[j] = (z[j] + beta[j]) * es[j];

        const float* vb1 = b1 + L * 32;
        const float* vb2 = b2 + L * 32;
        const float* vbf = bf + L * 8;

        // ---- W1 via MFMA: h1^T = W1^T(padded K=16) @ z1^T ----
        float zp0 = pkh(z[0], z[1]);
        float zp1 = pkh(z[2], z[3]);
        u32x2 s0 = pls(zp0, 0.f);
        u32x2 s1 = pls(zp1, 0.f);
        f16x8 Z0 = mk8(bcf(s0[0]), bcf(s1[0]), 0.f, 0.f);   // rows 0-31
        f16x8 Z1 = mk8(bcf(s0[1]), bcf(s1[1]), 0.f, 0.f);   // rows 32-63

        f32x16 g0 = {}, g1 = {};
        g0 = __builtin_amdgcn_mfma_f32_32x32x16_f16(W1A, Z0, g0, 0, 0, 0);
        g1 = __builtin_amdgcn_mfma_f32_32x32x16_f16(W1A, Z1, g1, 0, 0, 0);

        // bias + relu + pack to f16 pairs
        float qg0[8], qg1[8];
        {
            float h0[16], h1v[16];
            #pragma unroll
            for (int r = 0; r < 16; ++r) {
                int wlo = (r & 3) + 8 * (r >> 2);
                float bsel = lo ? vb1[wlo] : vb1[wlo + 4];
                float a = g0[r] + bsel; h0[r]  = a > 0.f ? a : 0.f;
                float b = g1[r] + bsel; h1v[r] = b > 0.f ? b : 0.f;
            }
            #pragma unroll
            for (int c = 0; c < 8; ++c) {
                qg0[c] = pkh(h0[2 * c], h0[2 * c + 1]);
                qg1[c] = pkh(h1v[2 * c], h1v[2 * c + 1]);
            }
        }

        // ---- W2 B-frags via permlane32_swap ----
        u32x2 pA = pls(qg0[0], qg0[2]);
        u32x2 pB = pls(qg0[1], qg0[3]);
        u32x2 pC = pls(qg0[4], qg0[6]);
        u32x2 pD = pls(qg0[5], qg0[7]);
        f16x8 B00 = mk8(bcf(pA[0]), bcf(pB[0]), bcf(pA[1]), bcf(pB[1]));
        f16x8 B01 = mk8(bcf(pC[0]), bcf(pD[0]), bcf(pC[1]), bcf(pD[1]));
        pA = pls(qg1[0], qg1[2]);
        pB = pls(qg1[1], qg1[3]);
        pC = pls(qg1[4], qg1[6]);
        pD = pls(qg1[5], qg1[7]);
        f16x8 B10 = mk8(bcf(pA[0]), bcf(pB[0]), bcf(pA[1]), bcf(pB[1]));
        f16x8 B11 = mk8(bcf(pC[0]), bcf(pD[0]), bcf(pC[1]), bcf(pD[1]));

        f32x16 d0 = {}, d1 = {};
        d0 = __builtin_amdgcn_mfma_f32_32x32x16_f16(A0, B00, d0, 0, 0, 0);
        d0 = __builtin_amdgcn_mfma_f32_32x32x16_f16(A1, B01, d0, 0, 0, 0);
        d1 = __builtin_amdgcn_mfma_f32_32x32x16_f16(A0, B10, d1, 0, 0, 0);
        d1 = __builtin_amdgcn_mfma_f32_32x32x16_f16(A1, B11, d1, 0, 0, 0);

        // ---- + b2, relu, pack ----
        float P0[8], P1[8];
        {
            float h2g0[16], h2g1[16];
            #pragma unroll
            for (int r = 0; r < 16; ++r) {
                int wlo = (r & 3) + 8 * (r >> 2);
                float bsel = lo ? vb2[wlo] : vb2[wlo + 4];
                float a = d0[r] + bsel; h2g0[r] = a > 0.f ? a : 0.f;
                float b = d1[r] + bsel; h2g1[r] = b > 0.f ? b : 0.f;
            }
            #pragma unroll
            for (int c = 0; c < 8; ++c) {
                P0[c] = pkh(h2g0[2 * c], h2g0[2 * c + 1]);
                P1[c] = pkh(h2g1[2 * c], h2g1[2 * c + 1]);
            }
        }

        // ---- Wf C-frags via permlane32_swap ----
        u32x2 pE = pls(P0[0], P0[2]);
        u32x2 pF = pls(P0[1], P0[3]);
        u32x2 pG = pls(P0[4], P0[6]);
        u32x2 pH = pls(P0[5], P0[7]);
        f16x8 C00 = mk8(bcf(pE[0]), bcf(pF[0]), bcf(pE[1]), bcf(pF[1]));
        f16x8 C01 = mk8(bcf(pG[0]), bcf(pH[0]), bcf(pG[1]), bcf(pH[1]));
        pE = pls(P1[0], P1[2]);
        pF = pls(P1[1], P1[3]);
        pG = pls(P1[4], P1[6]);
        pH = pls(P1[5], P1[7]);
        f16x8 C10 = mk8(bcf(pE[0]), bcf(pF[0]), bcf(pE[1]), bcf(pF[1]));
        f16x8 C11 = mk8(bcf(pG[0]), bcf(pH[0]), bcf(pG[1]), bcf(pH[1]));

        f32x16 e0 = {}, e1 = {};
        e0 = __builtin_amdgcn_mfma_f32_32x32x16_f16(F0, C00, e0, 0, 0, 0);
        e0 = __builtin_amdgcn_mfma_f32_32x32x16_f16(F1, C01, e0, 0, 0, 0);
        e1 = __builtin_amdgcn_mfma_f32_32x32x16_f16(F0, C10, e1, 0, 0, 0);
        e1 = __builtin_amdgcn_mfma_f32_32x32x16_f16(F1, C11, e1, 0, 0, 0);

        // ---- gather own row's h3 via permlane32_swap ----
        float h3[8];
        #pragma unroll
        for (int r = 0; r < 4; ++r) {
            u32x2 pe = pls(e0[r], e1[r]);
            h3[r]     = bcf(pe[0]) + vbf[r];
            h3[r + 4] = bcf(pe[1]) + vbf[r + 4];
        }

        // ---- coupling epilogue + permutation + next-layer partials ----
        float nacc[16];
        {
            float ldl = 0.f;
            float nz[8];
            #pragma unroll
            for (int j = 0; j < 4; ++j) {
                float sc = 0.6f * fast_tanh(h3[2 * j + 1]);
                float sh = gfac[j] * fast_tanh(h3[2 * j]);
                float z2 = z[4 + j];
                z2 = z2 + sc * z2 + sh;
                ldl += __logf(1.0f + sc);
                nz[3 - j] = z2;      // reversed: out[3-j] = z2_j
                nz[7 - j] = z[j];    // reversed: out[7-j] = z1_j
            }
            ldv += sum_s + ldl;
            #pragma unroll
            for (int j = 0; j < 8; ++j) {
                z[j] = nz[j];
                nacc[j]     = nz[j];
                nacc[8 + j] = nz[j] * nz[j];
            }
        }

        if (L < 7) {
            #pragma unroll
            for (int i = 0; i < 8; ++i) {
                float snd = (lane & 1) ? nacc[i] : nacc[8 + i];
                float kp  = (lane & 1) ? nacc[8 + i] : nacc[i];
                nacc[i] = kp + __shfl_xor(snd, 1, 64);
            }
            #pragma unroll
            for (int i = 0; i < 4; ++i) {
                float snd = (lane & 2) ? nacc[i] : nacc[4 + i];
                float kp  = (lane & 2) ? nacc[4 + i] : nacc[i];
                nacc[i] = kp + __shfl_xor(snd, 2, 64);
            }
            #pragma unroll
            for (int i = 0; i < 2; ++i) {
                float snd = (lane & 4) ? nacc[i] : nacc[2 + i];
                float kp  = (lane & 4) ? nacc[2 + i] : nacc[i];
                nacc[i] = kp + __shfl_xor(snd, 4, 64);
            }
            {
                float snd = (lane & 8) ? nacc[0] : nacc[1];
                float kp  = (lane & 8) ? nacc[1] : nacc[0];
                nacc[0] = kp + __shfl_xor(snd, 8, 64);
            }
            nacc[0] += __shfl_xor(nacc[0], 16, 64);
            nacc[0] += __shfl_xor(nacc[0], 32, 64);
            if (lane < 16) lred[wid * 16 + br] = nacc[0];
            __syncthreads();
            if (tid < 16) {
                float s = 0.f;
                #pragma unroll
                for (int w = 0; w < 16; ++w) s += lred[w * 16 + tid];
                __hip_atomic_fetch_add(slots + (size_t)(L + 1) * SLOT_L_DW +
                                           tid * 64 + slot, s,
                                       __ATOMIC_RELAXED, __HIP_MEMORY_SCOPE_AGENT);
            }
            gbar_stats(slots, stats, bar, (unsigned)(L + 2), L + 1,
                       logs, bvec, log_gamma, lred);
        }
    }

    // ---- store outputs: z (B,8) then ld (B,1) ----
    {
        float4* p0 = reinterpret_cast<float4*>(out + r0 * 8);
        float4 a, c;
        a.x=z[0]; a.y=z[1]; a.z=z[2]; a.w=z[3];
        c.x=z[4]; c.y=z[5]; c.z=z[6]; c.w=z[7];
        p0[0] = a; p0[1] = c;
    }
    out[(size_t)B_ROWS * 8 + r0] = ldv;
}

extern "C" void kernel_launch(void* const* d_in, const int* in_sizes, int n_in,
                              void* d_out, int out_size, void* d_ws, size_t ws_size,
                              hipStream_t stream) {
    const float* x      = (const float*)d_in[0];
    const float* logdet = (const float*)d_in[1];
    const float* bvec   = (const float*)d_in[2];
    const float* logs   = (const float*)d_in[3];
    const float* lg     = (const float*)d_in[4];
    const float* W1     = (const float*)d_in[5];
    const float* b1     = (const float*)d_in[6];
    const float* W2     = (const float*)d_in[7];
    const float* b2     = (const float*)d_in[8];
    const float* Wf     = (const float*)d_in[9];
    const float* bf     = (const float*)d_in[10];
    float* out = (float*)d_out;

    // ws layout: w1pk[8KB] | w2pk[16KB] | wfpk[16KB]
    //            | slots[SLOTS_TOT f32] | stats[STATS_TOT f32] | bar[BAR_DWORDS u32]
    f16*      w1pk  = (f16*)d_ws;
    f16*      w2pk  = w1pk + 4096;
    f16*      wfpk  = w2pk + 8192;
    float*    slots = (float*)(wfpk + 8192);
    float*    stats = slots + SLOTS_TOT;
    unsigned* bar   = (unsigned*)(stats + STATS_TOT);

    pack_weights<<<PKBLK, 256, 0, stream>>>(W1, W2, Wf, w1pk, w2pk, wfpk,
                                            slots, bar);

    void* args[] = {&x, &logdet, &bvec, &logs, &lg, &b1, &b2, &bf,
                    &w1pk, &w2pk, &wfpk, &out, &slots, &stats, &bar};
    hipLaunchKernel(reinterpret_cast<void*>(&flow_fused),
                    dim3(NBLK), dim3(TPB), args, 0, stream);
}